// Round 1
// baseline (157.919 us; speedup 1.0000x reference)
//
#include <hip/hip_runtime.h>

#define NS 8192
#define NE 4096
#define DIN 512
#define DK 64
#define DV 256
#define NCHUNK 8
#define CHUNK (NS / NCHUNK)   // 1024

typedef __attribute__((ext_vector_type(8))) short bf16x8;
typedef __attribute__((ext_vector_type(4))) short bf16x4;
typedef __attribute__((ext_vector_type(4))) float f32x4;
typedef __attribute__((ext_vector_type(8))) unsigned short ushort8;
typedef __attribute__((ext_vector_type(4))) unsigned short ushort4v;

#define L2E 1.44269504088896f

__device__ __forceinline__ unsigned short f2bf(float f) {
    union { float f; unsigned int u; } v; v.f = f;
    unsigned int u = v.u;
    unsigned int r = u + 0x7fffu + ((u >> 16) & 1u);   // RNE
    return (unsigned short)(r >> 16);
}

// ---------------------------------------------------------------------------
// proj: fused Q/K/V projections.  C = A(fp32,Mx512) @ B(fp32,512xN) -> bf16.
// blocks 0..63: Q = Y@Wq * 0.125 -> Qb[4096][64]
// blocks 64..191: K = X@Wk      -> Kb[8192][64]
// blocks 192..703: V = X@Wv     -> Vt[256][8192]  (transposed epilogue)
// ---------------------------------------------------------------------------
union ProjSmem {
    struct { unsigned short As[64][40]; unsigned short Bst[64][40]; } s;
    unsigned short Ct[64][72];
};

__global__ __launch_bounds__(256, 4) void proj_kernel(
    const float* __restrict__ X, const float* __restrict__ Y,
    const float* __restrict__ Wq, const float* __restrict__ Wk,
    const float* __restrict__ Wv,
    unsigned short* __restrict__ Qb, unsigned short* __restrict__ Kb,
    unsigned short* __restrict__ Vt) {

    int b = blockIdx.x;
    const float* A; const float* B; unsigned short* out;
    int N, m0, n0; float scale; bool tr;
    if (b < 64)       { A = Y; B = Wq; out = Qb; N = 64;  m0 = b * 64;        n0 = 0;            scale = 0.125f; tr = false; }
    else if (b < 192) { A = X; B = Wk; out = Kb; N = 64;  m0 = (b - 64) * 64; n0 = 0;            scale = 1.0f;   tr = false; }
    else              { int bb = b - 192;
                        A = X; B = Wv; out = Vt; N = 256; m0 = (bb >> 2) * 64; n0 = (bb & 3) * 64; scale = 1.0f; tr = true; }

    __shared__ ProjSmem sm;
    int tid = threadIdx.x;
    int lane = tid & 63, w = tid >> 6;
    int c = lane & 15, g = lane >> 4;
    int wr = w >> 1, wc = w & 1;

    f32x4 acc[2][2] = {};

    for (int kt = 0; kt < 16; ++kt) {
        int k0 = kt * 32;
        __syncthreads();
        #pragma unroll
        for (int it = 0; it < 2; ++it) {
            int idx = it * 256 + tid;
            {   // stage A tile: 64 rows x 32 k, fp32 -> bf16
                int r = idx >> 3, c4 = (idx & 7) * 4;
                float4 v = *(const float4*)&A[(size_t)(m0 + r) * DIN + k0 + c4];
                ushort4v t; t.x = f2bf(v.x); t.y = f2bf(v.y); t.z = f2bf(v.z); t.w = f2bf(v.w);
                *(ushort4v*)&sm.s.As[r][c4] = t;
            }
            {   // stage B tile transposed: Bst[n][k]
                int kk = idx >> 4, c4 = (idx & 15) * 4;
                float4 v = *(const float4*)&B[(size_t)(k0 + kk) * N + n0 + c4];
                sm.s.Bst[c4 + 0][kk] = f2bf(v.x);
                sm.s.Bst[c4 + 1][kk] = f2bf(v.y);
                sm.s.Bst[c4 + 2][kk] = f2bf(v.z);
                sm.s.Bst[c4 + 3][kk] = f2bf(v.w);
            }
        }
        __syncthreads();

        bf16x8 af[2], bfr[2];
        #pragma unroll
        for (int fr = 0; fr < 2; ++fr)
            af[fr] = *(const bf16x8*)&sm.s.As[wr * 32 + fr * 16 + c][8 * g];
        #pragma unroll
        for (int fc = 0; fc < 2; ++fc)
            bfr[fc] = *(const bf16x8*)&sm.s.Bst[wc * 32 + fc * 16 + c][8 * g];
        #pragma unroll
        for (int fr = 0; fr < 2; ++fr)
            #pragma unroll
            for (int fc = 0; fc < 2; ++fc)
                acc[fr][fc] = __builtin_amdgcn_mfma_f32_16x16x32_bf16(af[fr], bfr[fc], acc[fr][fc], 0, 0, 0);
    }

    if (!tr) {
        #pragma unroll
        for (int fr = 0; fr < 2; ++fr)
            #pragma unroll
            for (int fc = 0; fc < 2; ++fc)
                #pragma unroll
                for (int i = 0; i < 4; ++i) {
                    int row = wr * 32 + fr * 16 + 4 * g + i;
                    int col = wc * 32 + fc * 16 + c;
                    out[(size_t)(m0 + row) * N + n0 + col] = f2bf(acc[fr][fc][i] * scale);
                }
    } else {
        __syncthreads();
        #pragma unroll
        for (int fr = 0; fr < 2; ++fr)
            #pragma unroll
            for (int fc = 0; fc < 2; ++fc)
                #pragma unroll
                for (int i = 0; i < 4; ++i) {
                    int row = wr * 32 + fr * 16 + 4 * g + i;   // m (sample)
                    int col = wc * 32 + fc * 16 + c;           // n (vdim)
                    sm.Ct[col][row] = f2bf(acc[fr][fc][i]);
                }
        __syncthreads();
        int nl = tid >> 2, c16 = (tid & 3) * 16;
        ushort8 a0 = *(const ushort8*)&sm.Ct[nl][c16];
        ushort8 a1 = *(const ushort8*)&sm.Ct[nl][c16 + 8];
        *(ushort8*)&out[(size_t)(n0 + nl) * NS + m0 + c16] = a0;
        *(ushort8*)&out[(size_t)(n0 + nl) * NS + m0 + c16 + 8] = a1;
    }
}

// ---------------------------------------------------------------------------
// flash: S^T = K·Q^T per wave (16 edges), mask from H (global), online
// softmax in-register, PV via Vt A-operand (two b64 reads) + in-lane P B-op.
// grid: 512 blocks = 64 edge-tiles x 8 sample-chunks. Partials to ws.
// ---------------------------------------------------------------------------
__global__ __launch_bounds__(256, 2) void flash_kernel(
    const unsigned short* __restrict__ Qb, const unsigned short* __restrict__ Kb,
    const unsigned short* __restrict__ Vt, const int* __restrict__ H,
    float* __restrict__ pacc, float* __restrict__ pm, float* __restrict__ pl) {

    int bid = blockIdx.x;
    int eb = bid & 63, ch = bid >> 6;
    int e0 = eb * 64;
    int sbeg = ch * CHUNK;

    __shared__ unsigned short Ks[64][72];
    __shared__ unsigned short Vts[256][80];

    int tid = threadIdx.x, lane = tid & 63, w = tid >> 6;
    int c = lane & 15, g = lane >> 4;
    int eW = e0 + w * 16 + c;   // this lane's edge column

    bf16x8 qf[2];
    #pragma unroll
    for (int ks = 0; ks < 2; ++ks)
        qf[ks] = *(const bf16x8*)&Qb[(size_t)eW * DK + ks * 32 + 8 * g];

    f32x4 o[16] = {};
    float m = -1e30f, l = 0.0f;

    for (int t = 0; t < CHUNK / 64; ++t) {
        int s0 = sbeg + t * 64;

        // mask loads (consumed after S MFMAs; drain at the barrier)
        int hv[4][4];
        #pragma unroll
        for (int fr = 0; fr < 4; ++fr)
            #pragma unroll
            for (int i = 0; i < 4; ++i)
                hv[fr][i] = H[(size_t)(s0 + fr * 16 + 4 * g + i) * NE + eW];

        __syncthreads();
        #pragma unroll
        for (int it = 0; it < 2; ++it) {   // stage K tile [64][64]
            int idx = it * 256 + tid; int r = idx >> 3, cc = idx & 7;
            *(ushort8*)&Ks[r][cc * 8] = *(const ushort8*)&Kb[(size_t)(s0 + r) * DK + cc * 8];
        }
        #pragma unroll
        for (int it = 0; it < 8; ++it) {   // stage Vt tile [256][64]
            int idx = it * 256 + tid; int v = idx >> 3, cc = idx & 7;
            *(ushort8*)&Vts[v][cc * 8] = *(const ushort8*)&Vt[(size_t)v * NS + s0 + cc * 8];
        }
        __syncthreads();

        // S^T tile: rows = samples, cols = edges (this wave's 16)
        f32x4 st[4] = {};
        #pragma unroll
        for (int fr = 0; fr < 4; ++fr)
            #pragma unroll
            for (int ks = 0; ks < 2; ++ks) {
                bf16x8 a = *(const bf16x8*)&Ks[fr * 16 + c][ks * 32 + 8 * g];
                st[fr] = __builtin_amdgcn_mfma_f32_16x16x32_bf16(a, qf[ks], st[fr], 0, 0, 0);
            }

        // mask + tile max
        float p[4][4]; float pmax = -1e30f;
        #pragma unroll
        for (int fr = 0; fr < 4; ++fr)
            #pragma unroll
            for (int i = 0; i < 4; ++i) {
                float sv = hv[fr][i] ? st[fr][i] : -1e30f;
                p[fr][i] = sv;
                pmax = fmaxf(pmax, sv);
            }
        pmax = fmaxf(pmax, __shfl_xor(pmax, 16));
        pmax = fmaxf(pmax, __shfl_xor(pmax, 32));

        // defer-max rescale (THR=8)
        if (!__all(pmax <= m + 8.0f)) {
            float mn = fmaxf(m, pmax);
            float al = exp2f((m - mn) * L2E);
            l *= al;
            #pragma unroll
            for (int vb = 0; vb < 16; ++vb) o[vb] *= al;
            m = mn;
        }

        float lp = 0.0f;
        #pragma unroll
        for (int fr = 0; fr < 4; ++fr)
            #pragma unroll
            for (int i = 0; i < 4; ++i) {
                float e = exp2f((p[fr][i] - m) * L2E);
                p[fr][i] = e;
                lp += e;
            }
        lp += __shfl_xor(lp, 16);
        lp += __shfl_xor(lp, 32);
        l += lp;

        // pack P to bf16 pairs (lane-local, no shuffles needed)
        unsigned int pk[4][2];
        #pragma unroll
        for (int fr = 0; fr < 4; ++fr) {
            pk[fr][0] = ((unsigned int)f2bf(p[fr][1]) << 16) | f2bf(p[fr][0]);
            pk[fr][1] = ((unsigned int)f2bf(p[fr][3]) << 16) | f2bf(p[fr][2]);
        }

        // PV: out^T[v][e]; A = Vt rows (two b64 reads realize the k-slot perm)
        #pragma unroll
        for (int ks = 0; ks < 2; ++ks) {
            union { unsigned int u[4]; bf16x8 s; } bb;
            bb.u[0] = pk[2 * ks][0]; bb.u[1] = pk[2 * ks][1];
            bb.u[2] = pk[2 * ks + 1][0]; bb.u[3] = pk[2 * ks + 1][1];
            #pragma unroll
            for (int vb = 0; vb < 16; ++vb) {
                union { bf16x4 h[2]; bf16x8 s; } av;
                av.h[0] = *(const bf16x4*)&Vts[vb * 16 + c][ks * 32 + 4 * g];
                av.h[1] = *(const bf16x4*)&Vts[vb * 16 + c][ks * 32 + 16 + 4 * g];
                o[vb] = __builtin_amdgcn_mfma_f32_16x16x32_bf16(av.s, bb.s, o[vb], 0, 0, 0);
            }
        }
    }

    // epilogue: v-major partials for coalesced stores
    size_t base = (size_t)ch * DV * NE;
    #pragma unroll
    for (int vb = 0; vb < 16; ++vb)
        #pragma unroll
        for (int i = 0; i < 4; ++i)
            pacc[base + (size_t)(vb * 16 + 4 * g + i) * NE + eW] = o[vb][i];
    if (g == 0) {
        pm[ch * NE + eW] = m;
        pl[ch * NE + eW] = l;
    }
}

// ---------------------------------------------------------------------------
// combine: merge 8 chunk partials, LDS-transpose for coalesced fp32 writes.
// grid: 256 blocks = 64 edge-tiles x 4 v-tiles.
// ---------------------------------------------------------------------------
__global__ __launch_bounds__(256, 4) void combine_kernel(
    const float* __restrict__ pacc, const float* __restrict__ pm,
    const float* __restrict__ pl, float* __restrict__ out) {

    __shared__ float T[64][68];
    int bid = blockIdx.x;
    int eb = bid & 63, vb = bid >> 6;
    int e0 = eb * 64, v0 = vb * 64;
    int tid = threadIdx.x;
    int el = tid & 63, vh = tid >> 6;
    int e = e0 + el;

    float mv[NCHUNK]; float M = -1e30f;
    #pragma unroll
    for (int chn = 0; chn < NCHUNK; ++chn) {
        mv[chn] = pm[chn * NE + e];
        M = fmaxf(M, mv[chn]);
    }
    float den = 0.0f; float wch[NCHUNK];
    #pragma unroll
    for (int chn = 0; chn < NCHUNK; ++chn) {
        wch[chn] = exp2f((mv[chn] - M) * L2E);
        den += wch[chn] * pl[chn * NE + e];
    }
    float rden = 1.0f / den;

    #pragma unroll
    for (int k = 0; k < 16; ++k) {
        int vl = vh * 16 + k;
        float num = 0.0f;
        #pragma unroll
        for (int chn = 0; chn < NCHUNK; ++chn)
            num += wch[chn] * pacc[((size_t)chn * DV + v0 + vl) * NE + e];
        T[el][vl] = num * rden;
    }
    __syncthreads();

    int er = tid >> 2, c16 = (tid & 3) * 16;
    #pragma unroll
    for (int j = 0; j < 4; ++j) {
        float4 vv = *(const float4*)&T[er][c16 + 4 * j];
        *(float4*)&out[(size_t)(e0 + er) * DV + v0 + c16 + 4 * j] = vv;
    }
}

// ---------------------------------------------------------------------------
// workspace layout (bytes)
// ---------------------------------------------------------------------------
#define QB_OFF   0u
#define KB_OFF   (QB_OFF + (size_t)NE * DK * 2)            // 524288
#define VT_OFF   (KB_OFF + (size_t)NS * DK * 2)            // 1572864
#define PACC_OFF (VT_OFF + (size_t)DV * NS * 2)            // 5767168
#define PM_OFF   (PACC_OFF + (size_t)NCHUNK * DV * NE * 4) // 39321600
#define PL_OFF   (PM_OFF + (size_t)NCHUNK * NE * 4)        // 39452672

extern "C" void kernel_launch(void* const* d_in, const int* in_sizes, int n_in,
                              void* d_out, int out_size, void* d_ws, size_t ws_size,
                              hipStream_t stream) {
    const float* X  = (const float*)d_in[0];
    const float* Y  = (const float*)d_in[1];
    const int*   H  = (const int*)d_in[2];
    const float* Wq = (const float*)d_in[3];
    const float* Wk = (const float*)d_in[4];
    const float* Wv = (const float*)d_in[5];

    char* ws = (char*)d_ws;
    unsigned short* Qb = (unsigned short*)(ws + QB_OFF);
    unsigned short* Kb = (unsigned short*)(ws + KB_OFF);
    unsigned short* Vt = (unsigned short*)(ws + VT_OFF);
    float* pacc = (float*)(ws + PACC_OFF);
    float* pm   = (float*)(ws + PM_OFF);
    float* pl   = (float*)(ws + PL_OFF);

    proj_kernel<<<704, 256, 0, stream>>>(X, Y, Wq, Wk, Wv, Qb, Kb, Vt);
    flash_kernel<<<512, 256, 0, stream>>>(Qb, Kb, Vt, H, pacc, pm, pl);
    combine_kernel<<<256, 256, 0, stream>>>(pacc, pm, pl, (float*)d_out);
}